// Round 8
// baseline (216.286 us; speedup 1.0000x reference)
//
#include <hip/hip_runtime.h>

namespace {

constexpr int B = 32, G = 50, A = 3, C = 80, H = 52, W = 52;
constexpr int HW = H * W;               // 2704
constexpr int NCELLS = B * A * HW;      // 259584
constexpr int ATTRS = 5 + C;            // 85
constexpr float IMG_W = 416.0f, IMG_H = 416.0f;
constexpr float IGNORE_THR = 0.5f;

constexpr int NWIN = B * G;                      // 1600 winner slots (w = b*G+g)
constexpr int NCLR = B * G * A;                  // 4800 clear slots
constexpr int DVEC = NCELLS / 4;                 // 64896 float4 packs
constexpr int DB_ = (DVEC + 255) / 256;          // 254 dense blocks
constexpr int WIN_BLOCKS = NWIN / 4;             // 400 (4 waves/block, 1 wave/slot)
constexpr int CLR_WAVES = (NCLR + 63) / 64;      // 75
constexpr int CLR_BLOCKS = (CLR_WAVES + 3) / 4;  // 19
constexpr int FUSED_BLOCKS = DB_ + WIN_BLOCKS + CLR_BLOCKS;  // 673

// scaled anchors = ANCHORS / stride(=8): exact in fp32
__device__ __constant__ float SA0[A] = {1.25f, 2.0f, 4.125f};
__device__ __constant__ float SA1[A] = {1.625f, 3.75f, 2.875f};

// clamped softplus: min(log(1+e^x), 100) == -clip(log(sigmoid(-x)), -100)
__device__ __forceinline__ float sp(float x) {
    float s = fmaxf(x, 0.0f) + log1pf(expf(-fabsf(x)));
    return fminf(s, 100.0f);
}

// BCE(sigmoid(x), t) with torch-style log clamp at -100
__device__ __forceinline__ float bce_logit(float x, float t) {
    return t * sp(-x) + (1.0f - t) * sp(x);
}

// ---- 1. build: per-image LDS dedup -> positional records, no maps/atomics ----
// win_rec[b*G+g] = winner cell iff GT g is the last GT of image b claiming that
//                  cell (JAX scatter last-wins), else -1.
// clr_rec[(b*G+g)*A+a] = cell iff (g,a) is the FIRST entry clearing that cell
//                  (exactly-once subtraction), else -1.
__global__ __launch_bounds__(64) void build_kernel(const float* __restrict__ tgt,
                                                   int* __restrict__ win_rec,
                                                   int* __restrict__ clr_rec,
                                                   int* __restrict__ done) {
    __shared__ int cw[G];        // winner cell per GT
    __shared__ int cc[G * A];    // clear cell per (GT, anchor), -1 if iou<=thr
    int b = blockIdx.x;
    int g = threadIdx.x;
    if (b == 0 && g == 0) *done = 0;   // reset last-block counter for fused pass
    if (g < G) {
        const float* t = tgt + ((size_t)b * G + g) * 5;
        float gw = t[3] / IMG_W * (float)W;
        float gh = t[4] / IMG_H * (float)H;
        int gi = min(max((int)(t[1] / IMG_W * (float)W), 0), W - 1);
        int gj = min(max((int)(t[2] / IMG_H * (float)H), 0), H - 1);
        float area_g = (gw + 1.0f) * (gh + 1.0f);
        float best_iou = -1.0f;
        int best = 0;
#pragma unroll
        for (int a = 0; a < A; ++a) {
            float iw = fmaxf(fminf(gw, SA0[a]) + 1.0f, 0.0f);
            float ih = fmaxf(fminf(gh, SA1[a]) + 1.0f, 0.0f);
            float inter = iw * ih;
            float area_a = (SA0[a] + 1.0f) * (SA1[a] + 1.0f);
            float iou = inter / (area_g + area_a - inter + 1e-16f);
            if (iou > best_iou) { best_iou = iou; best = a; }  // first-max argmax
            cc[g * A + a] = (iou > IGNORE_THR) ? ((b * A + a) * H + gj) * W + gi : -1;
        }
        cw[g] = ((b * A + best) * H + gj) * W + gi;
    }
    __syncthreads();
    if (g < G) {
        int c = cw[g];
        int valid = 1;
        for (int g2 = g + 1; g2 < G; ++g2)
            if (cw[g2] == c) valid = 0;          // a later GT overwrites this cell
        win_rec[b * G + g] = valid ? c : -1;
    }
    for (int e = threadIdx.x; e < G * A; e += 64) {
        int c = cc[e];
        int v = (c >= 0);
        if (v)
            for (int e2 = 0; e2 < e; ++e2)
                if (cc[e2] == c) { v = 0; break; }  // already cleared earlier
        clr_rec[(size_t)b * G * A + e] = v ? c : -1;
    }
}

// ---- 2. fused: dense conf-noobj sum + winner terms + clear subtraction,
//         last-done block folds the final reduction ----
__global__ __launch_bounds__(256) void fused_kernel(
    const float* __restrict__ in, const float* __restrict__ tgt,
    const int* __restrict__ win_rec, const int* __restrict__ clr_rec,
    double* __restrict__ partials, int* __restrict__ done,
    float* __restrict__ out) {
    int lane = threadIdx.x & 63, wid = threadIdx.x >> 6;
    double m = 0.0, cl = 0.0, np = 0.0;

    if (blockIdx.x < DB_) {
        // dense: 0.5 * sp(conf_logit) over all cells, float4-vectorized
        int vid = blockIdx.x * 256 + threadIdx.x;
        if (vid < DVEC) {
            int plane = vid / (HW / 4);          // (b,a) pair, 0..95
            int off = (vid - plane * (HW / 4)) * 4;
            int b = plane / A, a = plane - b * A;
            const float4 v = *reinterpret_cast<const float4*>(
                in + ((size_t)(b * 255 + a * ATTRS + 4)) * HW + off);
            float s = sp(v.x) + sp(v.y) + sp(v.z) + sp(v.w);
            m = 0.5 * (double)s;
        }
    } else {
        int w = (blockIdx.x - DB_) * 4 + wid;    // global sparse wave id
        if (w < NWIN) {
            // one wave per winner slot; 85 attrs lane-parallel
            int cell = win_rec[w];
            if (cell >= 0) {
                int b = w / G;
                int a = (cell / HW) % A;
                int hw = cell % HW;
                const float* t = tgt + (size_t)w * 5;
                float gx = t[1] / IMG_W * (float)W;
                float gy = t[2] / IMG_H * (float)H;
                float gw = t[3] / IMG_W * (float)W;
                float gh = t[4] / IMG_H * (float)H;
                int gi = min(max((int)gx, 0), W - 1);
                int gj = min(max((int)gy, 0), H - 1);
                float tx = gx - (float)gi;
                float ty = gy - (float)gj;
                float tw = logf(gw / SA0[a] + 1e-16f);
                float th = logf(gh / SA1[a] + 1e-16f);
                int cls = min(max((int)t[0], 0), C - 1);
                const float* base = in + ((size_t)(b * 255 + a * ATTRS)) * HW + hw;
                float mf = 0.0f, clf = 0.0f;
#pragma unroll
                for (int rep = 0; rep < 2; ++rep) {
                    int attr = lane + rep * 64;
                    if (attr < ATTRS) {
                        float x = base[(size_t)attr * HW];
                        if (attr == 0) mf += 2.5f * bce_logit(x, tx);
                        else if (attr == 1) mf += 2.5f * bce_logit(x, ty);
                        else if (attr == 2) { float d = x - tw; mf += 2.5f * d * d; }
                        else if (attr == 3) { float d = x - th; mf += 2.5f * d * d; }
                        else if (attr == 4) mf += sp(-x);        // conf obj term
                        else clf += (attr - 5 == cls) ? sp(-x) : sp(x);
                    }
                }
                m = (double)mf;
                cl = (double)clf;
                np = (lane == 0) ? 1.0 : 0.0;
            }
        } else {
            // subtract cleared cells from the dense noobj sum
            int idx = (w - NWIN) * 64 + lane;
            if (idx < NCLR) {
                int cell = clr_rec[idx];
                if (cell >= 0) {
                    int hw = cell % HW;
                    int a = (cell / HW) % A;
                    int b = cell / (HW * A);
                    float x4 = in[((size_t)(b * 255 + a * ATTRS + 4)) * HW + hw];
                    m = -0.5 * (double)sp(x4);
                }
            }
        }
    }

    // block reduction of (m, cl, np)
    __shared__ double lm[4], lc[4], ln[4];
    for (int o = 32; o > 0; o >>= 1) {
        m += __shfl_down(m, o, 64);
        cl += __shfl_down(cl, o, 64);
        np += __shfl_down(np, o, 64);
    }
    if (lane == 0) { lm[wid] = m; lc[wid] = cl; ln[wid] = np; }
    __syncthreads();
    if (threadIdx.x == 0) {
        partials[(size_t)blockIdx.x * 3 + 0] = lm[0] + lm[1] + lm[2] + lm[3];
        partials[(size_t)blockIdx.x * 3 + 1] = lc[0] + lc[1] + lc[2] + lc[3];
        partials[(size_t)blockIdx.x * 3 + 2] = ln[0] + ln[1] + ln[2] + ln[3];
    }
    // last-done block performs the final reduction (rocPRIM-style)
    __shared__ int amLast;
    __threadfence();
    if (threadIdx.x == 0)
        amLast = (atomicAdd(done, 1) == FUSED_BLOCKS - 1);
    __syncthreads();
    if (amLast) {
        __threadfence();
        double M = 0.0, CL = 0.0, NP = 0.0;
        for (int k = threadIdx.x; k < FUSED_BLOCKS; k += 256) {
            M += partials[(size_t)k * 3 + 0];
            CL += partials[(size_t)k * 3 + 1];
            NP += partials[(size_t)k * 3 + 2];
        }
        for (int o = 32; o > 0; o >>= 1) {
            M += __shfl_down(M, o, 64);
            CL += __shfl_down(CL, o, 64);
            NP += __shfl_down(NP, o, 64);
        }
        __syncthreads();   // reuse of lm/lc/ln below
        if (lane == 0) { lm[wid] = M; lc[wid] = CL; ln[wid] = NP; }
        __syncthreads();
        if (threadIdx.x == 0) {
            double mt = lm[0] + lm[1] + lm[2] + lm[3];
            double ct = lc[0] + lc[1] + lc[2] + lc[3];
            double npos = ln[0] + ln[1] + ln[2] + ln[3];
            double denom = fmax(npos * (double)C, 1.0);
            out[0] = (float)(mt / (double)NCELLS + ct / denom);
        }
    }
}

}  // namespace

extern "C" void kernel_launch(void* const* d_in, const int* in_sizes, int n_in,
                              void* d_out, int out_size, void* d_ws, size_t ws_size,
                              hipStream_t stream) {
    const float* in = (const float*)d_in[0];   // [32,255,52,52] f32
    const float* tgt = (const float*)d_in[1];  // [32,50,5] f32
    float* out = (float*)d_out;

    // ws layout (all slots rewritten every call; 0xAA poison-safe):
    double* partials = (double*)d_ws;                    // FUSED_BLOCKS*3 doubles
    int* win_rec = (int*)(partials + (size_t)FUSED_BLOCKS * 3);  // NWIN ints
    int* clr_rec = win_rec + NWIN;                       // NCLR ints
    int* done = clr_rec + NCLR;                          // 1 int
    // total ws ≈ 16 KB + 25.6 KB + 4 B

    build_kernel<<<B, 64, 0, stream>>>(tgt, win_rec, clr_rec, done);
    fused_kernel<<<FUSED_BLOCKS, 256, 0, stream>>>(
        in, tgt, win_rec, clr_rec, partials, done, out);
}

// Round 10
// 150.324 us; speedup vs baseline: 1.4388x; 1.4388x over previous
//
#include <hip/hip_runtime.h>

namespace {

constexpr int B = 32, G = 50, A = 3, C = 80, H = 52, W = 52;
constexpr int HW = H * W;               // 2704
constexpr int NCELLS = B * A * HW;      // 259584
constexpr int ATTRS = 5 + C;            // 85
constexpr float IMG_W = 416.0f, IMG_H = 416.0f;
constexpr float IGNORE_THR = 0.5f;

constexpr int NWIN = B * G;                      // 1600 winner slots (w = b*G+g)
constexpr int NCLR = B * G * A;                  // 4800 clear slots
constexpr int DVEC = NCELLS / 4;                 // 64896 float4 packs
constexpr int DB_ = (DVEC + 255) / 256;          // 254 dense blocks
constexpr int WIN_BLOCKS = NWIN / 4;             // 400 (4 waves/block, 1 wave/slot)
constexpr int CLR_WAVES = (NCLR + 63) / 64;      // 75
constexpr int CLR_BLOCKS = (CLR_WAVES + 3) / 4;  // 19
constexpr int FUSED_BLOCKS = DB_ + WIN_BLOCKS + CLR_BLOCKS;  // 673

// scaled anchors = ANCHORS / stride(=8): exact in fp32
__device__ __constant__ float SA0[A] = {1.25f, 2.0f, 4.125f};
__device__ __constant__ float SA1[A] = {1.625f, 3.75f, 2.875f};

// clamped softplus: min(log(1+e^x), 100) == -clip(log(sigmoid(-x)), -100)
__device__ __forceinline__ float sp(float x) {
    float s = fmaxf(x, 0.0f) + log1pf(expf(-fabsf(x)));
    return fminf(s, 100.0f);
}

// BCE(sigmoid(x), t) with torch-style log clamp at -100
__device__ __forceinline__ float bce_logit(float x, float t) {
    return t * sp(-x) + (1.0f - t) * sp(x);
}

// ---- 1. build: per-image LDS dedup -> positional records, no maps/atomics ----
// win_rec[b*G+g] = winner cell iff GT g is the last GT of image b claiming that
//                  cell (JAX scatter last-wins), else -1.
// clr_rec[(b*G+g)*A+a] = cell iff (g,a) is the FIRST entry clearing that cell
//                  (exactly-once subtraction), else -1.
__global__ __launch_bounds__(64) void build_kernel(const float* __restrict__ tgt,
                                                   int* __restrict__ win_rec,
                                                   int* __restrict__ clr_rec) {
    __shared__ int cw[G];        // winner cell per GT
    __shared__ int cc[G * A];    // clear cell per (GT, anchor), -1 if iou<=thr
    int b = blockIdx.x;
    int g = threadIdx.x;
    if (g < G) {
        const float* t = tgt + ((size_t)b * G + g) * 5;
        float gw = t[3] / IMG_W * (float)W;
        float gh = t[4] / IMG_H * (float)H;
        int gi = min(max((int)(t[1] / IMG_W * (float)W), 0), W - 1);
        int gj = min(max((int)(t[2] / IMG_H * (float)H), 0), H - 1);
        float area_g = (gw + 1.0f) * (gh + 1.0f);
        float best_iou = -1.0f;
        int best = 0;
#pragma unroll
        for (int a = 0; a < A; ++a) {
            float iw = fmaxf(fminf(gw, SA0[a]) + 1.0f, 0.0f);
            float ih = fmaxf(fminf(gh, SA1[a]) + 1.0f, 0.0f);
            float inter = iw * ih;
            float area_a = (SA0[a] + 1.0f) * (SA1[a] + 1.0f);
            float iou = inter / (area_g + area_a - inter + 1e-16f);
            if (iou > best_iou) { best_iou = iou; best = a; }  // first-max argmax
            cc[g * A + a] = (iou > IGNORE_THR) ? ((b * A + a) * H + gj) * W + gi : -1;
        }
        cw[g] = ((b * A + best) * H + gj) * W + gi;
    }
    __syncthreads();
    if (g < G) {
        int c = cw[g];
        int valid = 1;
        for (int g2 = g + 1; g2 < G; ++g2)
            if (cw[g2] == c) valid = 0;          // a later GT overwrites this cell
        win_rec[b * G + g] = valid ? c : -1;
    }
    for (int e = threadIdx.x; e < G * A; e += 64) {
        int c = cc[e];
        int v = (c >= 0);
        if (v)
            for (int e2 = 0; e2 < e; ++e2)
                if (cc[e2] == c) { v = 0; break; }  // already cleared earlier
        clr_rec[(size_t)b * G * A + e] = v ? c : -1;
    }
}

// ---- 2. fused: dense conf-noobj sum + winner terms + clear subtraction ----
// NO device fence / done-counter here (R8 post-mortem: per-block
// __threadfence + device atomic => ~73us L2-writeback storm on gfx950;
// kernel boundary is one visibility point instead of 673).
__global__ __launch_bounds__(256) void fused_kernel(
    const float* __restrict__ in, const float* __restrict__ tgt,
    const int* __restrict__ win_rec, const int* __restrict__ clr_rec,
    double* __restrict__ partials) {
    int lane = threadIdx.x & 63, wid = threadIdx.x >> 6;
    double m = 0.0, cl = 0.0, np = 0.0;

    if (blockIdx.x < DB_) {
        // dense: 0.5 * sp(conf_logit) over all cells, float4-vectorized
        int vid = blockIdx.x * 256 + threadIdx.x;
        if (vid < DVEC) {
            int plane = vid / (HW / 4);          // (b,a) pair, 0..95
            int off = (vid - plane * (HW / 4)) * 4;
            int b = plane / A, a = plane - b * A;
            const float4 v = *reinterpret_cast<const float4*>(
                in + ((size_t)(b * 255 + a * ATTRS + 4)) * HW + off);
            float s = sp(v.x) + sp(v.y) + sp(v.z) + sp(v.w);
            m = 0.5 * (double)s;
        }
    } else {
        int w = (blockIdx.x - DB_) * 4 + wid;    // global sparse wave id
        if (w < NWIN) {
            // one wave per winner slot; 85 attrs lane-parallel
            int cell = win_rec[w];
            if (cell >= 0) {
                int b = w / G;
                int a = (cell / HW) % A;
                int hw = cell % HW;
                const float* t = tgt + (size_t)w * 5;
                float gx = t[1] / IMG_W * (float)W;
                float gy = t[2] / IMG_H * (float)H;
                float gw = t[3] / IMG_W * (float)W;
                float gh = t[4] / IMG_H * (float)H;
                int gi = min(max((int)gx, 0), W - 1);
                int gj = min(max((int)gy, 0), H - 1);
                float tx = gx - (float)gi;
                float ty = gy - (float)gj;
                float tw = logf(gw / SA0[a] + 1e-16f);
                float th = logf(gh / SA1[a] + 1e-16f);
                int cls = min(max((int)t[0], 0), C - 1);
                const float* base = in + ((size_t)(b * 255 + a * ATTRS)) * HW + hw;
                float mf = 0.0f, clf = 0.0f;
#pragma unroll
                for (int rep = 0; rep < 2; ++rep) {
                    int attr = lane + rep * 64;
                    if (attr < ATTRS) {
                        float x = base[(size_t)attr * HW];
                        if (attr == 0) mf += 2.5f * bce_logit(x, tx);
                        else if (attr == 1) mf += 2.5f * bce_logit(x, ty);
                        else if (attr == 2) { float d = x - tw; mf += 2.5f * d * d; }
                        else if (attr == 3) { float d = x - th; mf += 2.5f * d * d; }
                        else if (attr == 4) mf += sp(-x);        // conf obj term
                        else clf += (attr - 5 == cls) ? sp(-x) : sp(x);
                    }
                }
                m = (double)mf;
                cl = (double)clf;
                np = (lane == 0) ? 1.0 : 0.0;
            }
        } else {
            // subtract cleared cells from the dense noobj sum
            int idx = (w - NWIN) * 64 + lane;
            if (idx < NCLR) {
                int cell = clr_rec[idx];
                if (cell >= 0) {
                    int hw = cell % HW;
                    int a = (cell / HW) % A;
                    int b = cell / (HW * A);
                    float x4 = in[((size_t)(b * 255 + a * ATTRS + 4)) * HW + hw];
                    m = -0.5 * (double)sp(x4);
                }
            }
        }
    }

    // block reduction of (m, cl, np)
    __shared__ double lm[4], lc[4], ln[4];
    for (int o = 32; o > 0; o >>= 1) {
        m += __shfl_down(m, o, 64);
        cl += __shfl_down(cl, o, 64);
        np += __shfl_down(np, o, 64);
    }
    if (lane == 0) { lm[wid] = m; lc[wid] = cl; ln[wid] = np; }
    __syncthreads();
    if (threadIdx.x == 0) {
        partials[(size_t)blockIdx.x * 3 + 0] = lm[0] + lm[1] + lm[2] + lm[3];
        partials[(size_t)blockIdx.x * 3 + 1] = lc[0] + lc[1] + lc[2] + lc[3];
        partials[(size_t)blockIdx.x * 3 + 2] = ln[0] + ln[1] + ln[2] + ln[3];
    }
}

// ---- 3. finalize: one block reduces all partials ----
__global__ __launch_bounds__(256) void finalize_kernel(
    const double* __restrict__ partials, float* __restrict__ out) {
    int lane = threadIdx.x & 63, wid = threadIdx.x >> 6;
    double M = 0.0, CL = 0.0, NP = 0.0;
    for (int k = threadIdx.x; k < FUSED_BLOCKS; k += 256) {
        M += partials[(size_t)k * 3 + 0];
        CL += partials[(size_t)k * 3 + 1];
        NP += partials[(size_t)k * 3 + 2];
    }
    __shared__ double lm[4], lc[4], ln[4];
    for (int o = 32; o > 0; o >>= 1) {
        M += __shfl_down(M, o, 64);
        CL += __shfl_down(CL, o, 64);
        NP += __shfl_down(NP, o, 64);
    }
    if (lane == 0) { lm[wid] = M; lc[wid] = CL; ln[wid] = NP; }
    __syncthreads();
    if (threadIdx.x == 0) {
        double mt = lm[0] + lm[1] + lm[2] + lm[3];
        double ct = lc[0] + lc[1] + lc[2] + lc[3];
        double npos = ln[0] + ln[1] + ln[2] + ln[3];
        double denom = fmax(npos * (double)C, 1.0);
        out[0] = (float)(mt / (double)NCELLS + ct / denom);
    }
}

}  // namespace

extern "C" void kernel_launch(void* const* d_in, const int* in_sizes, int n_in,
                              void* d_out, int out_size, void* d_ws, size_t ws_size,
                              hipStream_t stream) {
    const float* in = (const float*)d_in[0];   // [32,255,52,52] f32
    const float* tgt = (const float*)d_in[1];  // [32,50,5] f32
    float* out = (float*)d_out;

    // ws layout (all slots rewritten every call; 0xAA poison-safe):
    double* partials = (double*)d_ws;                    // FUSED_BLOCKS*3 doubles
    int* win_rec = (int*)(partials + (size_t)FUSED_BLOCKS * 3);  // NWIN ints
    int* clr_rec = win_rec + NWIN;                       // NCLR ints
    // total ws ≈ 16 KB + 25.6 KB

    build_kernel<<<B, 64, 0, stream>>>(tgt, win_rec, clr_rec);
    fused_kernel<<<FUSED_BLOCKS, 256, 0, stream>>>(
        in, tgt, win_rec, clr_rec, partials);
    finalize_kernel<<<1, 256, 0, stream>>>(partials, out);
}

// Round 16
// 145.868 us; speedup vs baseline: 1.4827x; 1.0305x over previous
//
#include <hip/hip_runtime.h>

namespace {

constexpr int B = 32, G = 50, A = 3, C = 80, H = 52, W = 52;
constexpr int HW = H * W;               // 2704
constexpr int NCELLS = B * A * HW;      // 259584
constexpr int ATTRS = 5 + C;            // 85
constexpr float IMG_W = 416.0f, IMG_H = 416.0f;
constexpr float IGNORE_THR = 0.5f;

constexpr int NWIN = B * G;                  // 1600 winner waves (w = b*G+g)
constexpr int DVEC = NCELLS / 4;             // 64896 float4 packs
constexpr int DB_ = (DVEC + 255) / 256;      // 254 dense blocks
constexpr int WIN_BLOCKS = NWIN / 4;         // 400 (4 waves/block)
constexpr int CLR_BLOCKS = B / 4;            // 8 (one wave per image)
constexpr int FUSED_BLOCKS = DB_ + WIN_BLOCKS + CLR_BLOCKS;  // 662

// scaled anchors = ANCHORS / stride(=8): exact in fp32
__device__ __constant__ float SA0[A] = {1.25f, 2.0f, 4.125f};
__device__ __constant__ float SA1[A] = {1.625f, 3.75f, 2.875f};

// clamped softplus: min(log(1+e^x), 100) == -clip(log(sigmoid(-x)), -100)
__device__ __forceinline__ float sp(float x) {
    float s = fmaxf(x, 0.0f) + log1pf(expf(-fabsf(x)));
    return fminf(s, 100.0f);
}

// BCE(sigmoid(x), t) with torch-style log clamp at -100
__device__ __forceinline__ float bce_logit(float x, float t) {
    return t * sp(-x) + (1.0f - t) * sp(x);
}

// per-lane target prep for GT (b, l): anchor argmax (first-max) -> winner cell
__device__ __forceinline__ int prep(const float* __restrict__ tgt, int b, int l,
                                    float& gx, float& gy, float& gw, float& gh,
                                    float& clsf) {
    const float* t = tgt + ((size_t)b * G + l) * 5;
    clsf = t[0];
    gx = t[1] / IMG_W * (float)W;
    gy = t[2] / IMG_H * (float)H;
    gw = t[3] / IMG_W * (float)W;
    gh = t[4] / IMG_H * (float)H;
    int gi = min(max((int)gx, 0), W - 1);
    int gj = min(max((int)gy, 0), H - 1);
    float area_g = (gw + 1.0f) * (gh + 1.0f);
    float best_iou = -1.0f;
    int best = 0;
#pragma unroll
    for (int a = 0; a < A; ++a) {
        float iw = fmaxf(fminf(gw, SA0[a]) + 1.0f, 0.0f);
        float ih = fmaxf(fminf(gh, SA1[a]) + 1.0f, 0.0f);
        float inter = iw * ih;
        float area_a = (SA0[a] + 1.0f) * (SA1[a] + 1.0f);
        float iou = inter / (area_g + area_a - inter + 1e-16f);
        if (iou > best_iou) { best_iou = iou; best = a; }
    }
    return ((b * A + best) * H + gj) * W + gi;
}

// ---- 1. fused: dense conf-noobj sum + winner terms (in-wave dedup) +
//         clear subtraction (in-wave LDS dedup). 2 nodes total; no device
//         fences (R8 pitfall), no build round-trip (R10 follow-up).
__global__ __launch_bounds__(256) void fused_kernel(
    const float* __restrict__ in, const float* __restrict__ tgt,
    double* __restrict__ partials) {
    int lane = threadIdx.x & 63, wid = threadIdx.x >> 6;
    double m = 0.0, cl = 0.0, np = 0.0;
    __shared__ int ccells[4][G * A];   // used by clear blocks only (2.4 KB)
    __shared__ double lm[4], lc[4], ln[4];

    if (blockIdx.x < DB_) {
        // dense: 0.5 * sp(conf_logit) over all cells, float4-vectorized
        int vid = blockIdx.x * 256 + threadIdx.x;
        if (vid < DVEC) {
            int plane = vid / (HW / 4);          // (b,a) pair, 0..95
            int off = (vid - plane * (HW / 4)) * 4;
            int b = plane / A, a = plane - b * A;
            const float4 v = *reinterpret_cast<const float4*>(
                in + ((size_t)(b * 255 + a * ATTRS + 4)) * HW + off);
            float s = sp(v.x) + sp(v.y) + sp(v.z) + sp(v.w);
            m = 0.5 * (double)s;
        }
    } else if (blockIdx.x < DB_ + WIN_BLOCKS) {
        // one wave per GT (b,g); lane l preps GT l of the same image, then a
        // ballot decides last-claimant validity (JAX scatter last-wins).
        int w = (blockIdx.x - DB_) * 4 + wid;    // [0,1600)
        int b = w / G, g = w - b * G;
        float gx_l, gy_l, gw_l, gh_l, cls_l;
        int cell_l = 0x7fffffff;
        if (lane < G)
            cell_l = prep(tgt, b, lane, gx_l, gy_l, gw_l, gh_l, cls_l);
        int cell = __shfl(cell_l, g);
        unsigned long long dup =
            __ballot(lane < G && lane > g && cell_l == cell);
        if (dup == 0ULL) {                        // wave-uniform branch
            float gx = __shfl(gx_l, g), gy = __shfl(gy_l, g);
            float gw = __shfl(gw_l, g), gh = __shfl(gh_l, g);
            int cls = min(max((int)__shfl(cls_l, g), 0), C - 1);
            int a = (cell / HW) % A;
            int hw = cell % HW;
            int gi = min(max((int)gx, 0), W - 1);
            int gj = min(max((int)gy, 0), H - 1);
            float tx = gx - (float)gi, ty = gy - (float)gj;
            float tw = logf(gw / SA0[a] + 1e-16f);
            float th = logf(gh / SA1[a] + 1e-16f);
            const float* base = in + ((size_t)(b * 255 + a * ATTRS)) * HW + hw;
            float mf = 0.0f, clf = 0.0f;
#pragma unroll
            for (int rep = 0; rep < 2; ++rep) {
                int attr = lane + rep * 64;
                if (attr < ATTRS) {
                    float x = base[(size_t)attr * HW];
                    if (attr == 0) mf += 2.5f * bce_logit(x, tx);
                    else if (attr == 1) mf += 2.5f * bce_logit(x, ty);
                    else if (attr == 2) { float d = x - tw; mf += 2.5f * d * d; }
                    else if (attr == 3) { float d = x - th; mf += 2.5f * d * d; }
                    else if (attr == 4) mf += sp(-x);        // conf obj term
                    else clf += (attr - 5 == cls) ? sp(-x) : sp(x);
                }
            }
            m = (double)mf;
            cl = (double)clf;
            np = (lane == 0) ? 1.0 : 0.0;
        }
    } else {
        // clear: one wave per image; LDS first-occurrence dedup (same
        // semantics as the R6/R10 bit-exact build), subtract sp(x4) once
        // per distinct cleared cell.
        int img = (blockIdx.x - DB_ - WIN_BLOCKS) * 4 + wid;  // [0,32)
        if (lane < G) {
            const float* t = tgt + ((size_t)img * G + lane) * 5;
            float gw = t[3] / IMG_W * (float)W;
            float gh = t[4] / IMG_H * (float)H;
            int gi = min(max((int)(t[1] / IMG_W * (float)W), 0), W - 1);
            int gj = min(max((int)(t[2] / IMG_H * (float)H), 0), H - 1);
            float area_g = (gw + 1.0f) * (gh + 1.0f);
#pragma unroll
            for (int a = 0; a < A; ++a) {
                float iw = fmaxf(fminf(gw, SA0[a]) + 1.0f, 0.0f);
                float ih = fmaxf(fminf(gh, SA1[a]) + 1.0f, 0.0f);
                float inter = iw * ih;
                float area_a = (SA0[a] + 1.0f) * (SA1[a] + 1.0f);
                float iou = inter / (area_g + area_a - inter + 1e-16f);
                ccells[wid][lane * A + a] =
                    (iou > IGNORE_THR) ? ((img * A + a) * H + gj) * W + gi : -1;
            }
        }
        __syncthreads();   // all 4 waves of a clear block take this path
        for (int e = lane; e < G * A; e += 64) {
            int c = ccells[wid][e];
            if (c >= 0) {
                bool first = true;
                for (int e2 = 0; e2 < e; ++e2)
                    if (ccells[wid][e2] == c) { first = false; break; }
                if (first) {
                    int hw = c % HW;
                    int a = (c / HW) % A;
                    int b2 = c / (HW * A);
                    float x4 = in[((size_t)(b2 * 255 + a * ATTRS + 4)) * HW + hw];
                    m += -0.5 * (double)sp(x4);
                }
            }
        }
    }

    // block reduction of (m, cl, np)
    for (int o = 32; o > 0; o >>= 1) {
        m += __shfl_down(m, o, 64);
        cl += __shfl_down(cl, o, 64);
        np += __shfl_down(np, o, 64);
    }
    if (lane == 0) { lm[wid] = m; lc[wid] = cl; ln[wid] = np; }
    __syncthreads();
    if (threadIdx.x == 0) {
        partials[(size_t)blockIdx.x * 3 + 0] = lm[0] + lm[1] + lm[2] + lm[3];
        partials[(size_t)blockIdx.x * 3 + 1] = lc[0] + lc[1] + lc[2] + lc[3];
        partials[(size_t)blockIdx.x * 3 + 2] = ln[0] + ln[1] + ln[2] + ln[3];
    }
}

// ---- 2. finalize: one block reduces all partials ----
__global__ __launch_bounds__(256) void finalize_kernel(
    const double* __restrict__ partials, float* __restrict__ out) {
    int lane = threadIdx.x & 63, wid = threadIdx.x >> 6;
    double M = 0.0, CL = 0.0, NP = 0.0;
    for (int k = threadIdx.x; k < FUSED_BLOCKS; k += 256) {
        M += partials[(size_t)k * 3 + 0];
        CL += partials[(size_t)k * 3 + 1];
        NP += partials[(size_t)k * 3 + 2];
    }
    __shared__ double lm[4], lc[4], ln[4];
    for (int o = 32; o > 0; o >>= 1) {
        M += __shfl_down(M, o, 64);
        CL += __shfl_down(CL, o, 64);
        NP += __shfl_down(NP, o, 64);
    }
    if (lane == 0) { lm[wid] = M; lc[wid] = CL; ln[wid] = NP; }
    __syncthreads();
    if (threadIdx.x == 0) {
        double mt = lm[0] + lm[1] + lm[2] + lm[3];
        double ct = lc[0] + lc[1] + lc[2] + lc[3];
        double npos = ln[0] + ln[1] + ln[2] + ln[3];
        double denom = fmax(npos * (double)C, 1.0);
        out[0] = (float)(mt / (double)NCELLS + ct / denom);
    }
}

}  // namespace

extern "C" void kernel_launch(void* const* d_in, const int* in_sizes, int n_in,
                              void* d_out, int out_size, void* d_ws, size_t ws_size,
                              hipStream_t stream) {
    const float* in = (const float*)d_in[0];   // [32,255,52,52] f32
    const float* tgt = (const float*)d_in[1];  // [32,50,5] f32
    float* out = (float*)d_out;

    // ws: partials only (every slot rewritten every call; 0xAA poison-safe)
    double* partials = (double*)d_ws;          // FUSED_BLOCKS*3 doubles ~ 15.9 KB

    fused_kernel<<<FUSED_BLOCKS, 256, 0, stream>>>(in, tgt, partials);
    finalize_kernel<<<1, 256, 0, stream>>>(partials, out);
}